// Round 10
// baseline (181.748 us; speedup 1.0000x reference)
//
#include <hip/hip_runtime.h>

#define H_IMG 1080
#define W_IMG 1920
#define NPIX (H_IMG * W_IMG)

typedef __attribute__((ext_vector_type(8))) short bfrag8;   // 8 bf16 (4 VGPRs)
typedef __attribute__((ext_vector_type(4))) float facc4;    // MFMA accumulator

// ws layout (bytes): [0,131072) grid_t f32; [131072,147456) pk2; [147456,151552) pk3;
// [151552,159744) pk1
#define PK2_OFF 131072
#define PK3_OFF 147456
#define PK1_OFF 151552

__device__ __forceinline__ void split_bf16(float x, unsigned short& hi, unsigned short& lo) {
    unsigned xu = __float_as_uint(x);
    hi = (unsigned short)(xu >> 16);                       // trunc-bf16
    float hif = __uint_as_float(xu & 0xffff0000u);
    float lof = x - hif;                                   // exact remainder
    lo = (unsigned short)(__float_as_uint(lof) >> 16);
}

// prep: grid transpose + weight fragment pre-pack (unchanged, verified R3-R9).
// Fragment indexing (row=lane&15, k=8*(lane>>4)+i) is the MFMA *A* operand.
__global__ void prep_kernel(const float* __restrict__ grids,
                            const int* __restrict__ cam_idx,
                            const float* __restrict__ W1,
                            const float* __restrict__ W2,
                            const float* __restrict__ W3,
                            float* __restrict__ grid_t,
                            unsigned short* __restrict__ pk1,
                            unsigned short* __restrict__ pk2,
                            unsigned short* __restrict__ pk3) {
    int idx = blockIdx.x * 256 + threadIdx.x;
    {   // grids (N,F,L,GH,GW) -> grid_t (L,GH,GW,F)
        int f = idx & 15, x = (idx >> 4) & 15, y = (idx >> 8) & 15, z = (idx >> 12) & 7;
        int cam = cam_idx[0];
        grid_t[idx] = grids[(((cam * 16 + f) * 8 + z) * 16 + y) * 16 + x];
    }
    if (idx < 8192) {  // pk2[(((mt*2+s)*2+h)*64+lane)*8+i] = half of W2[j=mt*16+(lane&15)][k=32s+8g+i]
        int i = idx & 7, lane = (idx >> 3) & 63, h = (idx >> 9) & 1,
            s = (idx >> 10) & 1, mt = (idx >> 11) & 3;
        int j = mt * 16 + (lane & 15);
        int k = s * 32 + (lane >> 4) * 8 + i;
        unsigned short hi, lo;
        split_bf16(W2[j * 64 + k], hi, lo);
        pk2[idx] = h ? lo : hi;
    } else if (idx < 10240) {  // pk3: W3 (12x64) zero-padded to 16 rows
        int e = idx - 8192;
        int i = e & 7, lane = (e >> 3) & 63, h = (e >> 9) & 1, s = (e >> 10) & 1;
        int c = lane & 15;
        int k = s * 32 + (lane >> 4) * 8 + i;
        float x = (c < 12) ? W3[c * 64 + k] : 0.0f;
        unsigned short hi, lo;
        split_bf16(x, hi, lo);
        pk3[e] = h ? lo : hi;
    } else if (idx < 14336) {  // pk1: W1 (64x16) zero-padded to K=32
        int e = idx - 10240;
        int i = e & 7, lane = (e >> 3) & 63, h = (e >> 9) & 1, mt = (e >> 10) & 3;
        int j = mt * 16 + (lane & 15);
        int k = (lane >> 4) * 8 + i;
        float x = (k < 16) ? W1[j * 16 + k] : 0.0f;
        unsigned short hi, lo;
        split_bf16(x, hi, lo);
        pk1[e] = h ? lo : hi;
    }
}

// tanh(x) = 1 - 2/(e^{2x}+1); e^{2x} = 2^{x*2/ln2} -> single mul + v_exp_f32
__device__ __forceinline__ float fast_tanh(float x) {
    float e = exp2f(x * 2.8853900817779268f);
    return 1.0f - 2.0f * __builtin_amdgcn_rcpf(e + 1.0f);
}

// round-to-nearest bf16 pair pack: (rtn(o)<<16) | rtn(e)  — 2 add + 1 perm
__device__ __forceinline__ unsigned rtn_pair(float e, float o) {
    unsigned ue = __float_as_uint(e) + 0x8000u;
    unsigned uo = __float_as_uint(o) + 0x8000u;
    return __builtin_amdgcn_perm(uo, ue, 0x07060302u);
}

#define DS_FENCE() asm volatile("s_waitcnt lgkmcnt(0)" ::: "memory")
#define CBAR() asm volatile("" ::: "memory")
#define MFMA16(A, B, C) __builtin_amdgcn_mfma_f32_16x16x32_bf16((A), (B), (C), 0, 0, 0)

__global__ __launch_bounds__(256, 3)
void nbat_main(const float* __restrict__ rgb,
               const float* __restrict__ grid_t,
               const unsigned short* __restrict__ pk1,
               const unsigned short* __restrict__ pk2,
               const unsigned short* __restrict__ pk3,
               float* __restrict__ out) {
    // per-wave 12 KB (u32 idx):
    //  F area  [0,1024):   featTile [64 rows][4 uint4] (K=32 zero-pad), later
    //                      reused as h2 half-tile [32 rows][8 uint4] (K=64)
    //  H area  [1024,3072): h1 tile [64 rows][8 uint4] (K=64, RTN bf16x2)
    // Registers are the occupancy cap (R9: acc1+acc2=128 AGPR -> 2.56 waves).
    // L2/L3 run per 32-pixel half so acc2 is [4][2]=32 AGPR and never
    // overlaps acc1 -> peak ~145 total regs -> 3 waves/SIMD.
    __shared__ __align__(16) unsigned hbuf[4][3072];  // 48 KB/block

    const int tid = threadIdx.x;
    const int w = tid >> 6, l = tid & 63;
    const int g = l >> 4, cc = l & 15;
    unsigned* hb = hbuf[w];
    uint4* hb4 = (uint4*)hb;
    const int H4 = 256;  // uint4 offset of H area

    const int pixbase = blockIdx.x * 256 + w * 64;
    const int pix = pixbase + l;
    const int row = pix / W_IMG;
    const int col = pix - row * W_IMG;

    // ---- gray + trilinear ----
    float r = rgb[3 * pix + 0];
    float gch = rgb[3 * pix + 1];
    float b = rgb[3 * pix + 2];
    float gray = fminf(fmaxf(0.299f * r + 0.587f * gch + 0.114f * b, 0.0f), 1.0f);

    float z = fminf(fmaxf(gray * 7.0f, 0.0f), 7.0f);
    float y = (float)row * (15.0f / 1079.0f);
    float x = (float)col * (15.0f / 1919.0f);

    float zf = floorf(z), yf = floorf(y), xf = floorf(x);
    int z0 = (int)zf, y0 = (int)yf, x0 = (int)xf;
    int z1 = min(z0 + 1, 7), y1 = min(y0 + 1, 15), x1 = min(x0 + 1, 15);
    float wz = z - zf, wy = y - yf, wx = x - xf;

    float feat[16];
#pragma unroll
    for (int i = 0; i < 16; ++i) feat[i] = 0.0f;

    const float4* gt4 = (const float4*)grid_t;
#pragma unroll
    for (int cz = 0; cz < 2; ++cz) {
        int zz = cz ? z1 : z0;
        float wwz = cz ? wz : (1.0f - wz);
#pragma unroll
        for (int cy = 0; cy < 2; ++cy) {
            int yy = cy ? y1 : y0;
            float wwzy = wwz * (cy ? wy : (1.0f - wy));
#pragma unroll
            for (int cx = 0; cx < 2; ++cx) {
                int xx = cx ? x1 : x0;
                float wc = wwzy * (cx ? wx : (1.0f - wx));
                int base = ((zz * 16 + yy) * 16 + xx) * 4;
#pragma unroll
                for (int q = 0; q < 4; ++q) {
                    float4 v = gt4[base + q];
                    feat[4 * q + 0] = fmaf(wc, v.x, feat[4 * q + 0]);
                    feat[4 * q + 1] = fmaf(wc, v.y, feat[4 * q + 1]);
                    feat[4 * q + 2] = fmaf(wc, v.z, feat[4 * q + 2]);
                    feat[4 * q + 3] = fmaf(wc, v.w, feat[4 * q + 3]);
                }
            }
        }
    }

    // ---- stage featT tile (R9 layout): row p=l, chunks 0,1 data, 2,3 zero ----
    const int sl = (l >> 1) & 3;
    {
        uint4 q0, q1;
        q0.x = rtn_pair(feat[0], feat[1]);
        q0.y = rtn_pair(feat[2], feat[3]);
        q0.z = rtn_pair(feat[4], feat[5]);
        q0.w = rtn_pair(feat[6], feat[7]);
        q1.x = rtn_pair(feat[8], feat[9]);
        q1.y = rtn_pair(feat[10], feat[11]);
        q1.z = rtn_pair(feat[12], feat[13]);
        q1.w = rtn_pair(feat[14], feat[15]);
        uint4 zz4 = make_uint4(0u, 0u, 0u, 0u);
        hb4[l * 4 + (0 ^ sl)] = q0;
        hb4[l * 4 + (1 ^ sl)] = q1;
        hb4[l * 4 + (2 ^ sl)] = zz4;
        hb4[l * 4 + (3 ^ sl)] = zz4;
    }
    DS_FENCE();

    // transition: tanh 4 values (features 16mt+4g+rr of pixel-row prow),
    // RTN bf16x2, one b64 write into a full-K tile at u32 base `ubase`.
    // chunk c = 2mt + (g>>1) of 8; swizzle c ^ (prow&7).
    auto trans = [&](const facc4& v, int mt, int prow, int ubase)
        __attribute__((always_inline)) {
        float t0 = fast_tanh(v[0]);
        float t1 = fast_tanh(v[1]);
        float t2 = fast_tanh(v[2]);
        float t3 = fast_tanh(v[3]);
        unsigned A = rtn_pair(t0, t1);
        unsigned B = rtn_pair(t2, t3);
        int c = 2 * mt + (g >> 1);
        int u = ubase + prow * 32 + (((c ^ (prow & 7)) << 2) + ((g & 1) << 1));
        *(uint2*)(hb + u) = make_uint2(A, B);
    };

    // ---- layer 1: C1 = W1 (64x32pad) x featT (32 x 64pix); acc1[4][4] ----
    const bfrag8* pk1v = (const bfrag8*)pk1;
    facc4 acc1[4][4];
#pragma unroll
    for (int mt = 0; mt < 4; ++mt)
#pragma unroll
        for (int nt = 0; nt < 4; ++nt) acc1[mt][nt] = (facc4){0.f, 0.f, 0.f, 0.f};
    {
        bfrag8 w1h[4], w1l[4];
#pragma unroll
        for (int mt = 0; mt < 4; ++mt) {
            w1h[mt] = pk1v[(mt * 2 + 0) * 64 + l];
            w1l[mt] = pk1v[(mt * 2 + 1) * 64 + l];
        }
#pragma unroll
        for (int nt = 0; nt < 4; ++nt) {
            int p = cc + 16 * nt;
            uint4 bq = hb4[p * 4 + (g ^ ((p >> 1) & 3))];
            bfrag8 bf = __builtin_bit_cast(bfrag8, bq);
#pragma unroll
            for (int mt = 0; mt < 4; ++mt) {
                acc1[mt][nt] = MFMA16(w1l[mt], bf, acc1[mt][nt]);
                acc1[mt][nt] = MFMA16(w1h[mt], bf, acc1[mt][nt]);
            }
        }
    }

    // ---- transition ALL of h1 into H area (acc1 fully dead afterwards) ----
#pragma unroll
    for (int mt = 0; mt < 4; ++mt)
#pragma unroll
        for (int nt = 0; nt < 4; ++nt) trans(acc1[mt][nt], mt, cc + 16 * nt, 1024);
    DS_FENCE();

    // ---- layers 2+3 per 32-pixel half: acc2 is [4][2] = 32 AGPR ----
    const bfrag8* pk2v = (const bfrag8*)pk2;
    const bfrag8* pk3v = (const bfrag8*)pk3;
#pragma unroll
    for (int h = 0; h < 2; ++h) {
        // layer 2: C2 = W2 (64x64) x h1T[:, 32h:32h+32]
        facc4 acc2[4][2];
#pragma unroll
        for (int mt = 0; mt < 4; ++mt)
#pragma unroll
            for (int ntl = 0; ntl < 2; ++ntl) acc2[mt][ntl] = (facc4){0.f, 0.f, 0.f, 0.f};
#pragma unroll
        for (int s = 0; s < 2; ++s) {
            bfrag8 w2h[4], w2l[4];
#pragma unroll
            for (int mt = 0; mt < 4; ++mt) {
                w2h[mt] = pk2v[((mt * 2 + s) * 2 + 0) * 64 + l];
                w2l[mt] = pk2v[((mt * 2 + s) * 2 + 1) * 64 + l];
            }
#pragma unroll
            for (int ntl = 0; ntl < 2; ++ntl) {
                int p = cc + 16 * (2 * h + ntl);
                uint4 q = hb4[H4 + p * 8 + ((4 * s + g) ^ (p & 7))];
                bfrag8 bh = __builtin_bit_cast(bfrag8, q);
#pragma unroll
                for (int mt = 0; mt < 4; ++mt) {
                    acc2[mt][ntl] = MFMA16(w2l[mt], bh, acc2[mt][ntl]);
                    acc2[mt][ntl] = MFMA16(w2h[mt], bh, acc2[mt][ntl]);
                }
            }
        }

        // transition h2 half into F area (rows 0..31, K=64)
#pragma unroll
        for (int mt = 0; mt < 4; ++mt)
#pragma unroll
            for (int ntl = 0; ntl < 2; ++ntl) trans(acc2[mt][ntl], mt, cc + 16 * ntl, 0);
        DS_FENCE();

        // layer 3: O = W3 (16pad x 64) x h2T-half
        facc4 o3[2];
#pragma unroll
        for (int ntl = 0; ntl < 2; ++ntl) o3[ntl] = (facc4){0.f, 0.f, 0.f, 0.f};
#pragma unroll
        for (int s = 0; s < 2; ++s) {
            bfrag8 w3h = pk3v[(s * 2 + 0) * 64 + l];
            bfrag8 w3l = pk3v[(s * 2 + 1) * 64 + l];
#pragma unroll
            for (int ntl = 0; ntl < 2; ++ntl) {
                int pl = cc + 16 * ntl;
                uint4 q = hb4[pl * 8 + ((4 * s + g) ^ (pl & 7))];
                bfrag8 bh = __builtin_bit_cast(bfrag8, q);
                o3[ntl] = MFMA16(w3l, bh, o3[ntl]);
                o3[ntl] = MFMA16(w3h, bh, o3[ntl]);
            }
        }

        // store half: lane holds features 4g..4g+3 of pixels cc+16ntl; g==3 pad
        if (g < 3) {
#pragma unroll
            for (int ntl = 0; ntl < 2; ++ntl) {
                int p = pixbase + 32 * h + 16 * ntl + cc;
                *(float4*)(out + p * 12 + 4 * g) =
                    make_float4(o3[ntl][0], o3[ntl][1], o3[ntl][2], o3[ntl][3]);
            }
        }
        CBAR();  // half h+1's h2 writes stay after half h's L3 reads (DS in-order)
    }
}

extern "C" void kernel_launch(void* const* d_in, const int* in_sizes, int n_in,
                              void* d_out, int out_size, void* d_ws, size_t ws_size,
                              hipStream_t stream) {
    const float* rgb   = (const float*)d_in[0];
    const float* grids = (const float*)d_in[1];
    const float* W1    = (const float*)d_in[2];
    const float* W2    = (const float*)d_in[3];
    const float* W3    = (const float*)d_in[4];
    const int*   cam   = (const int*)d_in[5];

    float* grid_t = (float*)d_ws;
    unsigned short* pk2 = (unsigned short*)((char*)d_ws + PK2_OFF);
    unsigned short* pk3 = (unsigned short*)((char*)d_ws + PK3_OFF);
    unsigned short* pk1 = (unsigned short*)((char*)d_ws + PK1_OFF);

    hipLaunchKernelGGL(prep_kernel, dim3(128), dim3(256), 0, stream,
                       grids, cam, W1, W2, W3, grid_t, pk1, pk2, pk3);
    hipLaunchKernelGGL(nbat_main, dim3(NPIX / 256), dim3(256), 0, stream,
                       rgb, grid_t, pk1, pk2, pk3, (float*)d_out);
}

// Round 11
// 164.806 us; speedup vs baseline: 1.1028x; 1.1028x over previous
//
#include <hip/hip_runtime.h>

#define H_IMG 1080
#define W_IMG 1920
#define NPIX (H_IMG * W_IMG)

typedef __attribute__((ext_vector_type(8))) short bfrag8;   // 8 bf16 (4 VGPRs)
typedef __attribute__((ext_vector_type(4))) float facc4;    // MFMA accumulator

// ws layout (bytes): [0,131072) grid_t f32; [131072,147456) pk2; [147456,151552) pk3;
// [151552,159744) pk1
#define PK2_OFF 131072
#define PK3_OFF 147456
#define PK1_OFF 151552

__device__ __forceinline__ void split_bf16(float x, unsigned short& hi, unsigned short& lo) {
    unsigned xu = __float_as_uint(x);
    hi = (unsigned short)(xu >> 16);                       // trunc-bf16
    float hif = __uint_as_float(xu & 0xffff0000u);
    float lof = x - hif;                                   // exact remainder
    lo = (unsigned short)(__float_as_uint(lof) >> 16);
}

// prep: grid transpose + weight fragment pre-pack (unchanged, verified R3-R10).
// Fragment indexing (row=lane&15, k=8*(lane>>4)+i) is the MFMA *A* operand.
__global__ void prep_kernel(const float* __restrict__ grids,
                            const int* __restrict__ cam_idx,
                            const float* __restrict__ W1,
                            const float* __restrict__ W2,
                            const float* __restrict__ W3,
                            float* __restrict__ grid_t,
                            unsigned short* __restrict__ pk1,
                            unsigned short* __restrict__ pk2,
                            unsigned short* __restrict__ pk3) {
    int idx = blockIdx.x * 256 + threadIdx.x;
    {   // grids (N,F,L,GH,GW) -> grid_t (L,GH,GW,F)
        int f = idx & 15, x = (idx >> 4) & 15, y = (idx >> 8) & 15, z = (idx >> 12) & 7;
        int cam = cam_idx[0];
        grid_t[idx] = grids[(((cam * 16 + f) * 8 + z) * 16 + y) * 16 + x];
    }
    if (idx < 8192) {  // pk2[(((mt*2+s)*2+h)*64+lane)*8+i] = half of W2[j=mt*16+(lane&15)][k=32s+8g+i]
        int i = idx & 7, lane = (idx >> 3) & 63, h = (idx >> 9) & 1,
            s = (idx >> 10) & 1, mt = (idx >> 11) & 3;
        int j = mt * 16 + (lane & 15);
        int k = s * 32 + (lane >> 4) * 8 + i;
        unsigned short hi, lo;
        split_bf16(W2[j * 64 + k], hi, lo);
        pk2[idx] = h ? lo : hi;
    } else if (idx < 10240) {  // pk3: W3 (12x64) zero-padded to 16 rows
        int e = idx - 8192;
        int i = e & 7, lane = (e >> 3) & 63, h = (e >> 9) & 1, s = (e >> 10) & 1;
        int c = lane & 15;
        int k = s * 32 + (lane >> 4) * 8 + i;
        float x = (c < 12) ? W3[c * 64 + k] : 0.0f;
        unsigned short hi, lo;
        split_bf16(x, hi, lo);
        pk3[e] = h ? lo : hi;
    } else if (idx < 14336) {  // pk1: W1 (64x16) zero-padded to K=32
        int e = idx - 10240;
        int i = e & 7, lane = (e >> 3) & 63, h = (e >> 9) & 1, mt = (e >> 10) & 3;
        int j = mt * 16 + (lane & 15);
        int k = (lane >> 4) * 8 + i;
        float x = (k < 16) ? W1[j * 16 + k] : 0.0f;
        unsigned short hi, lo;
        split_bf16(x, hi, lo);
        pk1[e] = h ? lo : hi;
    }
}

// tanh(x) = 1 - 2/(e^{2x}+1); e^{2x} = 2^{x*2/ln2} -> single mul + v_exp_f32
__device__ __forceinline__ float fast_tanh(float x) {
    float e = exp2f(x * 2.8853900817779268f);
    return 1.0f - 2.0f * __builtin_amdgcn_rcpf(e + 1.0f);
}

// round-to-nearest bf16 pair pack: (rtn(o)<<16) | rtn(e)  — 2 add + 1 perm
__device__ __forceinline__ unsigned rtn_pair(float e, float o) {
    unsigned ue = __float_as_uint(e) + 0x8000u;
    unsigned uo = __float_as_uint(o) + 0x8000u;
    return __builtin_amdgcn_perm(uo, ue, 0x07060302u);
}

#define DS_FENCE() asm volatile("s_waitcnt lgkmcnt(0)" ::: "memory")
#define MFMA16(A, B, C) __builtin_amdgcn_mfma_f32_16x16x32_bf16((A), (B), (C), 0, 0, 0)

__global__ __launch_bounds__(256, 3)
void nbat_main(const float* __restrict__ rgb,
               const float* __restrict__ grid_t,
               const unsigned short* __restrict__ pk1,
               const unsigned short* __restrict__ pk2,
               const unsigned short* __restrict__ pk3,
               float* __restrict__ out) {
    // per-wave 12 KB (u32 idx):
    //  F area [0,1024):    featTile [64 rows][4 uint4] (K=32 zero-pad)
    //  H area [1024,3072): h tile [64 rows][8 uint4] (K=64, RTN bf16x2) —
    //                      holds h1 for L2, then overwritten with h2 for L3
    //                      (write-after-read safe: each row's writes depend via
    //                      acc2 on all reads of that row; DS is per-wave in-order)
    // Phase partition kills acc1/acc2 overlap (R9's 200-reg peak -> ~150):
    //  L1 (acc1 64 live) -> trans ALL h1 (acc1 dies) -> L2 (acc2 64) ->
    //  trans ALL h2 (acc2 dies) -> L3 (o3 16).
    __shared__ __align__(16) unsigned hbuf[4][3072];  // 48 KB/block

    const int tid = threadIdx.x;
    const int w = tid >> 6, l = tid & 63;
    const int g = l >> 4, cc = l & 15;
    unsigned* hb = hbuf[w];
    uint4* hb4 = (uint4*)hb;
    const int H4 = 256;  // uint4 offset of H area

    const int pixbase = blockIdx.x * 256 + w * 64;
    const int pix = pixbase + l;
    const int row = pix / W_IMG;
    const int col = pix - row * W_IMG;

    // ---- gray + trilinear ----
    float r = rgb[3 * pix + 0];
    float gch = rgb[3 * pix + 1];
    float b = rgb[3 * pix + 2];
    float gray = fminf(fmaxf(0.299f * r + 0.587f * gch + 0.114f * b, 0.0f), 1.0f);

    float z = fminf(fmaxf(gray * 7.0f, 0.0f), 7.0f);
    float y = (float)row * (15.0f / 1079.0f);
    float x = (float)col * (15.0f / 1919.0f);

    float zf = floorf(z), yf = floorf(y), xf = floorf(x);
    int z0 = (int)zf, y0 = (int)yf, x0 = (int)xf;
    int z1 = min(z0 + 1, 7), y1 = min(y0 + 1, 15), x1 = min(x0 + 1, 15);
    float wz = z - zf, wy = y - yf, wx = x - xf;

    float feat[16];
#pragma unroll
    for (int i = 0; i < 16; ++i) feat[i] = 0.0f;

    const float4* gt4 = (const float4*)grid_t;
#pragma unroll
    for (int cz = 0; cz < 2; ++cz) {
        int zz = cz ? z1 : z0;
        float wwz = cz ? wz : (1.0f - wz);
#pragma unroll
        for (int cy = 0; cy < 2; ++cy) {
            int yy = cy ? y1 : y0;
            float wwzy = wwz * (cy ? wy : (1.0f - wy));
#pragma unroll
            for (int cx = 0; cx < 2; ++cx) {
                int xx = cx ? x1 : x0;
                float wc = wwzy * (cx ? wx : (1.0f - wx));
                int base = ((zz * 16 + yy) * 16 + xx) * 4;
#pragma unroll
                for (int q = 0; q < 4; ++q) {
                    float4 v = gt4[base + q];
                    feat[4 * q + 0] = fmaf(wc, v.x, feat[4 * q + 0]);
                    feat[4 * q + 1] = fmaf(wc, v.y, feat[4 * q + 1]);
                    feat[4 * q + 2] = fmaf(wc, v.z, feat[4 * q + 2]);
                    feat[4 * q + 3] = fmaf(wc, v.w, feat[4 * q + 3]);
                }
            }
        }
    }

    // ---- stage featT tile (R9 layout): row p=l, chunks 0,1 data, 2,3 zero ----
    const int sl = (l >> 1) & 3;
    {
        uint4 q0, q1;
        q0.x = rtn_pair(feat[0], feat[1]);
        q0.y = rtn_pair(feat[2], feat[3]);
        q0.z = rtn_pair(feat[4], feat[5]);
        q0.w = rtn_pair(feat[6], feat[7]);
        q1.x = rtn_pair(feat[8], feat[9]);
        q1.y = rtn_pair(feat[10], feat[11]);
        q1.z = rtn_pair(feat[12], feat[13]);
        q1.w = rtn_pair(feat[14], feat[15]);
        uint4 zz4 = make_uint4(0u, 0u, 0u, 0u);
        hb4[l * 4 + (0 ^ sl)] = q0;
        hb4[l * 4 + (1 ^ sl)] = q1;
        hb4[l * 4 + (2 ^ sl)] = zz4;
        hb4[l * 4 + (3 ^ sl)] = zz4;
    }
    DS_FENCE();  // (1) feat writes -> L1 reads

    // transition: tanh 4 values (features 16mt+4g+rr of pixel-row prow),
    // RTN bf16x2, one b64 write into the H tile (K=64).  [R10-validated layout]
    // chunk c = 2mt + (g>>1) of 8; swizzle c ^ (prow&7).
    auto trans = [&](const facc4& v, int mt, int prow) __attribute__((always_inline)) {
        float t0 = fast_tanh(v[0]);
        float t1 = fast_tanh(v[1]);
        float t2 = fast_tanh(v[2]);
        float t3 = fast_tanh(v[3]);
        unsigned A = rtn_pair(t0, t1);
        unsigned B = rtn_pair(t2, t3);
        int c = 2 * mt + (g >> 1);
        int u = 1024 + prow * 32 + (((c ^ (prow & 7)) << 2) + ((g & 1) << 1));
        *(uint2*)(hb + u) = make_uint2(A, B);
    };

    // ---- layer 1: C1 = W1 (64x32pad) x featT (32 x 64pix); acc1[4][4] ----
    const bfrag8* pk1v = (const bfrag8*)pk1;
    facc4 acc1[4][4];
#pragma unroll
    for (int mt = 0; mt < 4; ++mt)
#pragma unroll
        for (int nt = 0; nt < 4; ++nt) acc1[mt][nt] = (facc4){0.f, 0.f, 0.f, 0.f};
    {
        bfrag8 w1h[4], w1l[4];
#pragma unroll
        for (int mt = 0; mt < 4; ++mt) {
            w1h[mt] = pk1v[(mt * 2 + 0) * 64 + l];
            w1l[mt] = pk1v[(mt * 2 + 1) * 64 + l];
        }
#pragma unroll
        for (int nt = 0; nt < 4; ++nt) {
            int p = cc + 16 * nt;
            uint4 bq = hb4[p * 4 + (g ^ ((p >> 1) & 3))];
            bfrag8 bf = __builtin_bit_cast(bfrag8, bq);
#pragma unroll
            for (int mt = 0; mt < 4; ++mt) {
                acc1[mt][nt] = MFMA16(w1l[mt], bf, acc1[mt][nt]);
                acc1[mt][nt] = MFMA16(w1h[mt], bf, acc1[mt][nt]);
            }
        }
    }

    // ---- transition ALL of h1 into H area: acc1 fully dead afterwards ----
#pragma unroll
    for (int mt = 0; mt < 4; ++mt)
#pragma unroll
        for (int nt = 0; nt < 4; ++nt) trans(acc1[mt][nt], mt, cc + 16 * nt);
    DS_FENCE();  // (2) h1 writes -> L2 reads

    // ---- layer 2 (full width): C2 = W2 (64x64) x h1T; acc2[4][4] ----
    const bfrag8* pk2v = (const bfrag8*)pk2;
    facc4 acc2[4][4];
#pragma unroll
    for (int mt = 0; mt < 4; ++mt)
#pragma unroll
        for (int nt = 0; nt < 4; ++nt) acc2[mt][nt] = (facc4){0.f, 0.f, 0.f, 0.f};
#pragma unroll
    for (int s = 0; s < 2; ++s) {
        bfrag8 w2h[4], w2l[4];
#pragma unroll
        for (int mt = 0; mt < 4; ++mt) {
            w2h[mt] = pk2v[((mt * 2 + s) * 2 + 0) * 64 + l];
            w2l[mt] = pk2v[((mt * 2 + s) * 2 + 1) * 64 + l];
        }
#pragma unroll
        for (int nt = 0; nt < 4; ++nt) {
            int p = cc + 16 * nt;
            uint4 q = hb4[H4 + p * 8 + ((4 * s + g) ^ (p & 7))];
            bfrag8 bh = __builtin_bit_cast(bfrag8, q);
#pragma unroll
            for (int mt = 0; mt < 4; ++mt) {
                acc2[mt][nt] = MFMA16(w2l[mt], bh, acc2[mt][nt]);
                acc2[mt][nt] = MFMA16(w2h[mt], bh, acc2[mt][nt]);
            }
        }
    }

    // ---- transition ALL of h2 into H area (overwrites h1; WAR safe by dep) ----
#pragma unroll
    for (int mt = 0; mt < 4; ++mt)
#pragma unroll
        for (int nt = 0; nt < 4; ++nt) trans(acc2[mt][nt], mt, cc + 16 * nt);
    DS_FENCE();  // (3) h2 writes -> L3 reads

    // ---- layer 3 (full width): O = W3 (16pad x 64) x h2T; o3[4] ----
    const bfrag8* pk3v = (const bfrag8*)pk3;
    facc4 o3[4];
#pragma unroll
    for (int nt = 0; nt < 4; ++nt) o3[nt] = (facc4){0.f, 0.f, 0.f, 0.f};
#pragma unroll
    for (int s = 0; s < 2; ++s) {
        bfrag8 w3h = pk3v[(s * 2 + 0) * 64 + l];
        bfrag8 w3l = pk3v[(s * 2 + 1) * 64 + l];
#pragma unroll
        for (int nt = 0; nt < 4; ++nt) {
            int p = cc + 16 * nt;
            uint4 q = hb4[H4 + p * 8 + ((4 * s + g) ^ (p & 7))];
            bfrag8 bh = __builtin_bit_cast(bfrag8, q);
            o3[nt] = MFMA16(w3l, bh, o3[nt]);
            o3[nt] = MFMA16(w3h, bh, o3[nt]);
        }
    }

    // ---- store: lane holds out features 4g..4g+3 for pixels cc+16nt; g==3 pad ----
    if (g < 3) {
#pragma unroll
        for (int nt = 0; nt < 4; ++nt) {
            int p = pixbase + 16 * nt + cc;
            *(float4*)(out + p * 12 + 4 * g) =
                make_float4(o3[nt][0], o3[nt][1], o3[nt][2], o3[nt][3]);
        }
    }
}

extern "C" void kernel_launch(void* const* d_in, const int* in_sizes, int n_in,
                              void* d_out, int out_size, void* d_ws, size_t ws_size,
                              hipStream_t stream) {
    const float* rgb   = (const float*)d_in[0];
    const float* grids = (const float*)d_in[1];
    const float* W1    = (const float*)d_in[2];
    const float* W2    = (const float*)d_in[3];
    const float* W3    = (const float*)d_in[4];
    const int*   cam   = (const int*)d_in[5];

    float* grid_t = (float*)d_ws;
    unsigned short* pk2 = (unsigned short*)((char*)d_ws + PK2_OFF);
    unsigned short* pk3 = (unsigned short*)((char*)d_ws + PK3_OFF);
    unsigned short* pk1 = (unsigned short*)((char*)d_ws + PK1_OFF);

    hipLaunchKernelGGL(prep_kernel, dim3(128), dim3(256), 0, stream,
                       grids, cam, W1, W2, W3, grid_t, pk1, pk2, pk3);
    hipLaunchKernelGGL(nbat_main, dim3(NPIX / 256), dim3(256), 0, stream,
                       rgb, grid_t, pk1, pk2, pk3, (float*)d_out);
}

// Round 12
// 149.168 us; speedup vs baseline: 1.2184x; 1.1048x over previous
//
#include <hip/hip_runtime.h>

#define H_IMG 1080
#define W_IMG 1920
#define NPIX (H_IMG * W_IMG)

typedef __attribute__((ext_vector_type(8))) short bfrag8;   // 8 bf16 (4 VGPRs)
typedef __attribute__((ext_vector_type(4))) float facc4;    // MFMA accumulator

// ws layout (bytes): [0,131072) grid_t f32; [131072,147456) pk2; [147456,151552) pk3;
// [151552,159744) pk1
#define PK2_OFF 131072
#define PK3_OFF 147456
#define PK1_OFF 151552

__device__ __forceinline__ void split_bf16(float x, unsigned short& hi, unsigned short& lo) {
    unsigned xu = __float_as_uint(x);
    hi = (unsigned short)(xu >> 16);                       // trunc-bf16
    float hif = __uint_as_float(xu & 0xffff0000u);
    float lof = x - hif;                                   // exact remainder
    lo = (unsigned short)(__float_as_uint(lof) >> 16);
}

// prep: grid transpose + weight fragment pre-pack (verified R3-R11).
// Fragment indexing (row=lane&15, k=8*(lane>>4)+i) is the MFMA *A* operand.
__global__ void prep_kernel(const float* __restrict__ grids,
                            const int* __restrict__ cam_idx,
                            const float* __restrict__ W1,
                            const float* __restrict__ W2,
                            const float* __restrict__ W3,
                            float* __restrict__ grid_t,
                            unsigned short* __restrict__ pk1,
                            unsigned short* __restrict__ pk2,
                            unsigned short* __restrict__ pk3) {
    int idx = blockIdx.x * 256 + threadIdx.x;
    {   // grids (N,F,L,GH,GW) -> grid_t (L,GH,GW,F)
        int f = idx & 15, x = (idx >> 4) & 15, y = (idx >> 8) & 15, z = (idx >> 12) & 7;
        int cam = cam_idx[0];
        grid_t[idx] = grids[(((cam * 16 + f) * 8 + z) * 16 + y) * 16 + x];
    }
    if (idx < 8192) {  // pk2[(((mt*2+s)*2+h)*64+lane)*8+i] = half of W2[j=mt*16+(lane&15)][k=32s+8g+i]
        int i = idx & 7, lane = (idx >> 3) & 63, h = (idx >> 9) & 1,
            s = (idx >> 10) & 1, mt = (idx >> 11) & 3;
        int j = mt * 16 + (lane & 15);
        int k = s * 32 + (lane >> 4) * 8 + i;
        unsigned short hi, lo;
        split_bf16(W2[j * 64 + k], hi, lo);
        pk2[idx] = h ? lo : hi;
    } else if (idx < 10240) {  // pk3: W3 (12x64) zero-padded to 16 rows
        int e = idx - 8192;
        int i = e & 7, lane = (e >> 3) & 63, h = (e >> 9) & 1, s = (e >> 10) & 1;
        int c = lane & 15;
        int k = s * 32 + (lane >> 4) * 8 + i;
        float x = (c < 12) ? W3[c * 64 + k] : 0.0f;
        unsigned short hi, lo;
        split_bf16(x, hi, lo);
        pk3[e] = h ? lo : hi;
    } else if (idx < 14336) {  // pk1: W1 (64x16) zero-padded to K=32
        int e = idx - 10240;
        int i = e & 7, lane = (e >> 3) & 63, h = (e >> 9) & 1, mt = (e >> 10) & 3;
        int j = mt * 16 + (lane & 15);
        int k = (lane >> 4) * 8 + i;
        float x = (k < 16) ? W1[j * 16 + k] : 0.0f;
        unsigned short hi, lo;
        split_bf16(x, hi, lo);
        pk1[e] = h ? lo : hi;
    }
}

__device__ __forceinline__ float fast_tanh(float x) {
    float e = __expf(2.0f * x);
    return 1.0f - 2.0f * __builtin_amdgcn_rcpf(e + 1.0f);
}

// (bf16_trunc(o)<<16) | bf16_trunc(e)  — one v_perm
__device__ __forceinline__ unsigned pack_hi_pair(float e, float o) {
    return __builtin_amdgcn_perm(__float_as_uint(o), __float_as_uint(e), 0x07060302u);
}

#define DS_FENCE() asm volatile("s_waitcnt lgkmcnt(0)" ::: "memory")
#define MFMA16(A, B, C) __builtin_amdgcn_mfma_f32_16x16x32_bf16((A), (B), (C), 0, 0, 0)
#define PRIO_HI() __builtin_amdgcn_s_setprio(1)
#define PRIO_LO() __builtin_amdgcn_s_setprio(0)

__global__ __launch_bounds__(256, 3)
void nbat_main(const float* __restrict__ rgb,
               const float* __restrict__ grid_t,
               const unsigned short* __restrict__ pk1,
               const unsigned short* __restrict__ pk2,
               const unsigned short* __restrict__ pk3,
               float* __restrict__ out) {
    // R5 structure (best measured: 150.5 us bench / 183 rocprof), plus T5
    // s_setprio around MFMA bursts (waves are free-running -> phase-diverse).
    // per-wave 8 KB: hiTile [64 p][16 u32] at [0,1024), loTile at [1024,2048)
    // u32 addr in row: chunk c(=k/8, 0..3) swizzled c ^= (p>>1)&3
    __shared__ __align__(16) unsigned hbuf[4][2048];  // 32 KB/block

    const int tid = threadIdx.x;
    const int w = tid >> 6, l = tid & 63;
    const int g = l >> 4, cc = l & 15;
    unsigned* hb = hbuf[w];
    uint4* hb4 = (uint4*)hb;

    const int pixbase = blockIdx.x * 256 + w * 64;
    const int pix = pixbase + l;
    const int row = pix / W_IMG;
    const int col = pix - row * W_IMG;

    // ---- gray + trilinear ----
    float r = rgb[3 * pix + 0];
    float gch = rgb[3 * pix + 1];
    float b = rgb[3 * pix + 2];
    float gray = fminf(fmaxf(0.299f * r + 0.587f * gch + 0.114f * b, 0.0f), 1.0f);

    float z = fminf(fmaxf(gray * 7.0f, 0.0f), 7.0f);
    float y = (float)row * (15.0f / 1079.0f);
    float x = (float)col * (15.0f / 1919.0f);

    float zf = floorf(z), yf = floorf(y), xf = floorf(x);
    int z0 = (int)zf, y0 = (int)yf, x0 = (int)xf;
    int z1 = min(z0 + 1, 7), y1 = min(y0 + 1, 15), x1 = min(x0 + 1, 15);
    float wz = z - zf, wy = y - yf, wx = x - xf;

    float feat[16];
#pragma unroll
    for (int i = 0; i < 16; ++i) feat[i] = 0.0f;

    const float4* gt4 = (const float4*)grid_t;
#pragma unroll
    for (int cz = 0; cz < 2; ++cz) {
        int zz = cz ? z1 : z0;
        float wwz = cz ? wz : (1.0f - wz);
#pragma unroll
        for (int cy = 0; cy < 2; ++cy) {
            int yy = cy ? y1 : y0;
            float wwzy = wwz * (cy ? wy : (1.0f - wy));
#pragma unroll
            for (int cx = 0; cx < 2; ++cx) {
                int xx = cx ? x1 : x0;
                float wc = wwzy * (cx ? wx : (1.0f - wx));
                int base = ((zz * 16 + yy) * 16 + xx) * 4;
#pragma unroll
                for (int q = 0; q < 4; ++q) {
                    float4 v = gt4[base + q];
                    feat[4 * q + 0] = fmaf(wc, v.x, feat[4 * q + 0]);
                    feat[4 * q + 1] = fmaf(wc, v.y, feat[4 * q + 1]);
                    feat[4 * q + 2] = fmaf(wc, v.z, feat[4 * q + 2]);
                    feat[4 * q + 3] = fmaf(wc, v.w, feat[4 * q + 3]);
                }
            }
        }
    }

    // ---- stage featT tile: row p=l holds feat[k] bf16, k 0..15, chunks 2,3 zero ----
    const int sl = (l >> 1) & 3;
    {
        uint4 q0, q1;
        q0.x = pack_hi_pair(feat[0], feat[1]);
        q0.y = pack_hi_pair(feat[2], feat[3]);
        q0.z = pack_hi_pair(feat[4], feat[5]);
        q0.w = pack_hi_pair(feat[6], feat[7]);
        q1.x = pack_hi_pair(feat[8], feat[9]);
        q1.y = pack_hi_pair(feat[10], feat[11]);
        q1.z = pack_hi_pair(feat[12], feat[13]);
        q1.w = pack_hi_pair(feat[14], feat[15]);
        uint4 zz4 = make_uint4(0u, 0u, 0u, 0u);
        hb4[l * 4 + (0 ^ sl)] = q0;
        hb4[l * 4 + (1 ^ sl)] = q1;
        hb4[l * 4 + (2 ^ sl)] = zz4;
        hb4[l * 4 + (3 ^ sl)] = zz4;
    }
    DS_FENCE();

    // transition: tanh 4 acc values (features +4g+rr, pixel cc+16nt),
    // exact hi/lo split, one b64 write per tile
    auto transition = [&](const facc4& v, int mtl, int nt) __attribute__((always_inline)) {
        float t0 = fast_tanh(v[0]);
        float t1 = fast_tanh(v[1]);
        float t2 = fast_tanh(v[2]);
        float t3 = fast_tanh(v[3]);
        unsigned hA = pack_hi_pair(t0, t1);
        unsigned hB = pack_hi_pair(t2, t3);
        float l0 = t0 - __uint_as_float(hA << 16);
        float l1 = t1 - __uint_as_float(hA & 0xffff0000u);
        float l2 = t2 - __uint_as_float(hB << 16);
        float l3 = t3 - __uint_as_float(hB & 0xffff0000u);
        unsigned lA = pack_hi_pair(l0, l1);
        unsigned lB = pack_hi_pair(l2, l3);
        int p = cc + 16 * nt;
        int u = p * 16 + ((((mtl << 1) + (g >> 1)) ^ ((p >> 1) & 3)) << 2) + ((g & 1) << 1);
        *(uint2*)(hb + u) = make_uint2(hA, hB);
        *(uint2*)(hb + 1024 + u) = make_uint2(lA, lB);
    };

    // ---- layer 1: C1 = W1 (64x32pad) x featT (32 x 64pix); acts 1-level ----
    const bfrag8* pk1v = (const bfrag8*)pk1;
    facc4 acc1[4][4];
#pragma unroll
    for (int mt = 0; mt < 4; ++mt)
#pragma unroll
        for (int nt = 0; nt < 4; ++nt) acc1[mt][nt] = (facc4){0.f, 0.f, 0.f, 0.f};
    {
        bfrag8 w1h[4], w1l[4];
#pragma unroll
        for (int mt = 0; mt < 4; ++mt) {
            w1h[mt] = pk1v[(mt * 2 + 0) * 64 + l];
            w1l[mt] = pk1v[(mt * 2 + 1) * 64 + l];
        }
#pragma unroll
        for (int nt = 0; nt < 4; ++nt) {
            int p = cc + 16 * nt;
            uint4 bq = hb4[p * 4 + (g ^ ((p >> 1) & 3))];
            bfrag8 bf = __builtin_bit_cast(bfrag8, bq);
            PRIO_HI();
#pragma unroll
            for (int mt = 0; mt < 4; ++mt) {
                acc1[mt][nt] = MFMA16(w1l[mt], bf, acc1[mt][nt]);
                acc1[mt][nt] = MFMA16(w1h[mt], bf, acc1[mt][nt]);
            }
            PRIO_LO();
        }
    }
    DS_FENCE();

    // ---- layer 2: C2 = W2 (64x64) x h1T, K-split s=0,1 through the 8 KB tiles ----
    const bfrag8* pk2v = (const bfrag8*)pk2;
    facc4 acc2[4][4];
#pragma unroll
    for (int mt = 0; mt < 4; ++mt)
#pragma unroll
        for (int nt = 0; nt < 4; ++nt) acc2[mt][nt] = (facc4){0.f, 0.f, 0.f, 0.f};

#pragma unroll
    for (int s = 0; s < 2; ++s) {
#pragma unroll
        for (int mtl = 0; mtl < 2; ++mtl)
#pragma unroll
            for (int nt = 0; nt < 4; ++nt) transition(acc1[2 * s + mtl][nt], mtl, nt);
        DS_FENCE();
        bfrag8 w2h[4], w2l[4];
#pragma unroll
        for (int mt = 0; mt < 4; ++mt) {
            w2h[mt] = pk2v[((mt * 2 + s) * 2 + 0) * 64 + l];
            w2l[mt] = pk2v[((mt * 2 + s) * 2 + 1) * 64 + l];
        }
#pragma unroll
        for (int nt = 0; nt < 4; ++nt) {
            int p = cc + 16 * nt;
            int sw = (p >> 1) & 3;
            uint4 qh = hb4[p * 4 + (g ^ sw)];
            uint4 ql = hb4[256 + p * 4 + (g ^ sw)];
            bfrag8 bh = __builtin_bit_cast(bfrag8, qh);
            bfrag8 bl = __builtin_bit_cast(bfrag8, ql);
            PRIO_HI();
#pragma unroll
            for (int mt = 0; mt < 4; ++mt) {
                acc2[mt][nt] = MFMA16(w2h[mt], bl, acc2[mt][nt]);
                acc2[mt][nt] = MFMA16(w2l[mt], bh, acc2[mt][nt]);
                acc2[mt][nt] = MFMA16(w2h[mt], bh, acc2[mt][nt]);
            }
            PRIO_LO();
        }
        DS_FENCE();
    }

    // ---- layer 3: O = W3 (16pad x 64) x h2T ----
    const bfrag8* pk3v = (const bfrag8*)pk3;
    facc4 o3[4];
#pragma unroll
    for (int nt = 0; nt < 4; ++nt) o3[nt] = (facc4){0.f, 0.f, 0.f, 0.f};

#pragma unroll
    for (int s = 0; s < 2; ++s) {
#pragma unroll
        for (int mtl = 0; mtl < 2; ++mtl)
#pragma unroll
            for (int nt = 0; nt < 4; ++nt) transition(acc2[2 * s + mtl][nt], mtl, nt);
        DS_FENCE();
        bfrag8 w3h = pk3v[(s * 2 + 0) * 64 + l];
        bfrag8 w3l = pk3v[(s * 2 + 1) * 64 + l];
#pragma unroll
        for (int nt = 0; nt < 4; ++nt) {
            int p = cc + 16 * nt;
            int sw = (p >> 1) & 3;
            uint4 qh = hb4[p * 4 + (g ^ sw)];
            uint4 ql = hb4[256 + p * 4 + (g ^ sw)];
            bfrag8 bh = __builtin_bit_cast(bfrag8, qh);
            bfrag8 bl = __builtin_bit_cast(bfrag8, ql);
            PRIO_HI();
            o3[nt] = MFMA16(w3h, bl, o3[nt]);
            o3[nt] = MFMA16(w3l, bh, o3[nt]);
            o3[nt] = MFMA16(w3h, bh, o3[nt]);
            PRIO_LO();
        }
        if (s == 0) DS_FENCE();
    }

    // ---- store: lane holds out features 4g..4g+3 for pixels cc+16nt; g==3 pad ----
    if (g < 3) {
#pragma unroll
        for (int nt = 0; nt < 4; ++nt) {
            int p = pixbase + 16 * nt + cc;
            *(float4*)(out + p * 12 + 4 * g) =
                make_float4(o3[nt][0], o3[nt][1], o3[nt][2], o3[nt][3]);
        }
    }
}

extern "C" void kernel_launch(void* const* d_in, const int* in_sizes, int n_in,
                              void* d_out, int out_size, void* d_ws, size_t ws_size,
                              hipStream_t stream) {
    const float* rgb   = (const float*)d_in[0];
    const float* grids = (const float*)d_in[1];
    const float* W1    = (const float*)d_in[2];
    const float* W2    = (const float*)d_in[3];
    const float* W3    = (const float*)d_in[4];
    const int*   cam   = (const int*)d_in[5];

    float* grid_t = (float*)d_ws;
    unsigned short* pk2 = (unsigned short*)((char*)d_ws + PK2_OFF);
    unsigned short* pk3 = (unsigned short*)((char*)d_ws + PK3_OFF);
    unsigned short* pk1 = (unsigned short*)((char*)d_ws + PK1_OFF);

    hipLaunchKernelGGL(prep_kernel, dim3(128), dim3(256), 0, stream,
                       grids, cam, W1, W2, W3, grid_t, pk1, pk2, pk3);
    hipLaunchKernelGGL(nbat_main, dim3(NPIX / 256), dim3(256), 0, stream,
                       rgb, grid_t, pk1, pk2, pk3, (float*)d_out);
}